// Round 2
// baseline (73.031 us; speedup 1.0000x reference)
//
#include <hip/hip_runtime.h>
#include <hip/hip_bf16.h>
#include <stdint.h>

#define IMG   224
#define OUTD  256
#define BATCH 256
#define JD    25
#define TD    64
#define MIDJ  12
#define BOXR  20

// workspace layout (bytes)
//   P     : bf16 [224][225][256]  = 25,804,800 B
//   runs  : u32  [256][224][32]   =  7,340,032 B
//   part  : f32  [256][8][256]    =  2,097,152 B
#define OFF_RUNS 25804800u
#define OFF_PART 33144832u

// ---------------- K1: column-prefix sums of W, stored bf16 [x][y][o] ----------
// Block = (x, o-chunk of 64). Coalesced load of a 64x224 fp32 tile of W into
// LDS (transpose staging), segmented prefix over y, coalesced bf16 writes
// over o. Replaces the round-1 version whose lanes read 200KB-apart addrs.
__global__ void k_wpref(const float* __restrict__ W, __hip_bfloat16* __restrict__ P) {
    const int x  = blockIdx.x;          // 0..223
    const int o0 = blockIdx.y * 64;     // o-chunk base
    const int tid = threadIdx.x;        // 0..255

    __shared__ float lds[64][225];      // [o_local][y], pad to 225 (bank-safe)
    __shared__ float carry[4][64];

    // coalesced load: 64 rows (o) x 224 cols (y), consecutive tid -> consecutive y
    for (int k = tid; k < 64 * 224; k += 256) {
        const int r = k / 224;
        const int y = k - r * 224;
        lds[r][y] = W[(size_t)(o0 + r) * (IMG * IMG) + (size_t)x * IMG + y];
    }
    __syncthreads();

    // segmented prefix: wave `seg` owns y in [seg*56, seg*56+56), lane = o_local
    const int ol  = tid & 63;
    const int seg = tid >> 6;
    const int y0  = seg * 56;

    float ssum = 0.0f;
    #pragma unroll 8
    for (int i = 0; i < 56; ++i) ssum += lds[ol][y0 + i];
    carry[seg][ol] = ssum;
    __syncthreads();

    float s = 0.0f;
    for (int s2 = 0; s2 < seg; ++s2) s += carry[s2][ol];

    __hip_bfloat16* p = P + ((size_t)x * 225) * 256 + o0 + ol;
    if (seg == 0) p[0] = __float2bfloat16(0.0f);
    #pragma unroll 8
    for (int i = 0; i < 56; ++i) {
        s += lds[ol][y0 + i];
        p[(size_t)(y0 + i + 1) * 256] = __float2bfloat16(s);  // 128B/wave store
    }
}

// ---------------- K2: per-batch argmax boxes + per-x run lists ----------------
__global__ void k_boxes_runs(const float* __restrict__ skel, uint32_t* __restrict__ runs) {
    const int b = blockIdx.x;
    const int wave = threadIdx.x >> 6;
    const int t = threadIdx.x & 63;
    __shared__ int s_px[JD], s_ylo[JD], s_yhi[JD];

    const float* sb = skel + (size_t)b * JD * TD * 3;
    // middle-joint coords for this frame
    const float mx = sb[(MIDJ * TD + t) * 3 + 0];
    const float my = sb[(MIDJ * TD + t) * 3 + 1];
    const float mz = sb[(MIDJ * TD + t) * 3 + 2];

    for (int j = wave; j < JD; j += 4) {
        const float ax = sb[(j * TD + t) * 3 + 0];
        const float ay = sb[(j * TD + t) * 3 + 1];
        const float az = sb[(j * TD + t) * 3 + 2];
        const float dx = ax - mx, dy = ay - my, dz = az - mz;
        // match numpy: no fma contraction, left-to-right adds, IEEE sqrt
        const float d2 = __fadd_rn(__fadd_rn(__fmul_rn(dx, dx), __fmul_rn(dy, dy)),
                                   __fmul_rn(dz, dz));
        float bd = sqrtf(d2);
        int   bi = t;
        #pragma unroll
        for (int off = 1; off < 64; off <<= 1) {
            const float od = __shfl_xor(bd, off);
            const int   oi = __shfl_xor(bi, off);
            if (od > bd || (od == bd && oi < bi)) { bd = od; bi = oi; }
        }
        if (t == 0) {
            const float ptx = sb[(j * TD + bi) * 3 + 0];
            const float pty = sb[(j * TD + bi) * 3 + 1];
            const int px = (int)(ptx * 224.0f);
            const int py = (int)(pty * 224.0f);
            s_px[j]  = px;
            s_ylo[j] = (py < BOXR) ? 0 : (py - BOXR);
            s_yhi[j] = (py > IMG - BOXR) ? IMG : (py + BOXR);
        }
    }
    __syncthreads();

    const int x = threadIdx.x;
    if (x >= IMG) return;

    // 224-bit coverage bitmap over y, in 4 named u64 words (no scratch arrays)
    unsigned long long m0 = 0, m1 = 0, m2 = 0, m3 = 0;
    for (int j = 0; j < JD; ++j) {
        if (j == MIDJ) continue;
        const int px = s_px[j];
        if (x >= px - BOXR && x < px + BOXR) {
            const int lo = s_ylo[j], hi = s_yhi[j];
            auto setw = [&](unsigned long long& mw, int wbase) {
                int l = lo - wbase; int h = hi - wbase;
                l = l < 0 ? 0 : l; h = h > 64 ? 64 : h;
                if (l < h) {
                    unsigned long long msk =
                        (h - l == 64) ? ~0ull : ((((1ull << (h - l)) - 1ull)) << l);
                    mw |= msk;
                }
            };
            setw(m0, 0); setw(m1, 64); setw(m2, 128); setw(m3, 192);
        }
    }

    uint32_t* rb = runs + ((size_t)b * IMG + x) * 32;
    int n = 0, start = -1;
    auto scanw = [&](unsigned long long bits, int wbase) {
        int pos = 0;
        while (pos < 64) {
            if (start < 0) {
                const unsigned long long tt = bits >> pos;
                if (!tt) return;                 // no more set bits in this word
                pos += __builtin_ctzll(tt);
                start = wbase + pos;
            } else {
                const unsigned long long tt = (~bits) >> pos;
                if (!tt) return;                 // run continues into next word
                pos += __builtin_ctzll(tt);
                rb[1 + n] = (uint32_t)start | ((uint32_t)(wbase + pos) << 8);
                ++n; start = -1;
            }
        }
    };
    scanw(m0, 0); scanw(m1, 64); scanw(m2, 128); scanw(m3, 192);
    if (start >= 0) { rb[1 + n] = (uint32_t)start | (224u << 8); ++n; }
    rb[0] = (uint32_t)n;
}

// ---------------- K3: accumulate run endpoint diffs over prefix table --------
// blockIdx = b*8 + s keeps all blocks of x-slice s on one XCD (round-robin),
// so each XCD's P working set is ~3.2MB (fits 4MB L2).
__global__ void k_accum(const uint32_t* __restrict__ runs,
                        const uint32_t* __restrict__ P32,   // P viewed as bf16x2
                        float* __restrict__ part) {
    const int b = blockIdx.x >> 3;
    const int s = blockIdx.x & 7;
    const int tid = threadIdx.x;    // 0..127 -> outputs 2*tid, 2*tid+1
    float a0 = 0.0f, a1 = 0.0f;
    const int x0 = s * 28;
    for (int x = x0; x < x0 + 28; ++x) {
        const uint32_t* rb = runs + ((size_t)b * IMG + x) * 32;
        const int n = (int)rb[0];
        const uint32_t* px = P32 + (size_t)x * 225 * 128 + tid;
        for (int i = 0; i < n; ++i) {
            const uint32_t ru = rb[1 + i];
            const int a = (int)(ru & 255u);
            const int c = (int)((ru >> 8) & 511u);
            const uint32_t va = px[(size_t)a * 128];
            const uint32_t vc = px[(size_t)c * 128];
            a0 += __uint_as_float(vc << 16) - __uint_as_float(va << 16);
            a1 += __uint_as_float(vc & 0xffff0000u) - __uint_as_float(va & 0xffff0000u);
        }
    }
    float* pp = part + (((size_t)b * 8 + s) * 256) + (size_t)tid * 2;
    pp[0] = a0;
    pp[1] = a1;
}

// ---------------- K4: out = rgb * (bias + sum of partials) -------------------
__global__ void k_final(const float* __restrict__ rgb, const float* __restrict__ bias,
                        const float* __restrict__ part, float* __restrict__ out) {
    const int idx = blockIdx.x * 256 + threadIdx.x;
    const int b = idx >> 8, o = idx & 255;
    float m = bias[o];
    #pragma unroll
    for (int s = 0; s < 8; ++s) m += part[(((size_t)b * 8 + s) * 256) + o];
    out[idx] = rgb[idx] * m;
}

extern "C" void kernel_launch(void* const* d_in, const int* in_sizes, int n_in,
                              void* d_out, int out_size, void* d_ws, size_t ws_size,
                              hipStream_t stream) {
    const float* rgb  = (const float*)d_in[0];
    const float* skel = (const float*)d_in[1];
    const float* W    = (const float*)d_in[2];
    const float* bias = (const float*)d_in[3];
    float* out = (float*)d_out;

    uint8_t* ws = (uint8_t*)d_ws;
    __hip_bfloat16* P = (__hip_bfloat16*)(ws);
    uint32_t* runs = (uint32_t*)(ws + OFF_RUNS);
    float* part = (float*)(ws + OFF_PART);

    k_wpref<<<dim3(IMG, 4), dim3(256), 0, stream>>>(W, P);
    k_boxes_runs<<<dim3(BATCH), dim3(256), 0, stream>>>(skel, runs);
    k_accum<<<dim3(BATCH * 8), dim3(128), 0, stream>>>(runs, (const uint32_t*)P, part);
    k_final<<<dim3(BATCH), dim3(256), 0, stream>>>(rgb, bias, part, out);
}

// Round 3
// 48.160 us; speedup vs baseline: 1.5164x; 1.5164x over previous
//
#include <hip/hip_runtime.h>
#include <hip/hip_bf16.h>
#include <stdint.h>

#define IMG   224
#define OUTD  256
#define BATCH 256
#define JD    25
#define TD    64
#define MIDJ  12
#define BOXR  20

// workspace layout (bytes)
//   P     : bf16 [224][225][256]  = 25,804,800
//   runs  : u32  [256][224][32]   =  7,340,032   (<=12 entries used per (b,x))
//   part  : f32  [256][8][256]    =  2,097,152
//   cnt   : u8   [256][224]       =     57,344
#define OFF_RUNS 25804800u
#define OFF_PART 33144832u
#define OFF_CNT  35241984u

// ---------------- K1: column-prefix sums of W, stored bf16 [x][y][o] ----------
// Block = (x, o-chunk of 32). 29.8KB LDS -> 5 blocks/CU (round-2 used 57.9KB
// -> 2/CU, no phase overlap). Coalesced scalar loads, pad-225 conflict-free.
__global__ void k_wpref(const float* __restrict__ W, __hip_bfloat16* __restrict__ P) {
    const int x  = blockIdx.x;          // 0..223
    const int o0 = blockIdx.y * 32;     // o-chunk base
    const int tid = threadIdx.x;        // 0..255

    __shared__ float lds[32][225];      // [o_local][y], pad 225: bank-safe both phases
    __shared__ float carry[8][32];

    // coalesced load: 32 rows (o) x 224 cols (y); consecutive tid -> consecutive y
    #pragma unroll
    for (int it = 0; it < 28; ++it) {
        const int k = it * 256 + tid;   // 0..7167 = 32*224
        const int r = k / 224;
        const int y = k - r * 224;
        lds[r][y] = W[(size_t)(o0 + r) * (IMG * IMG) + (size_t)x * IMG + y];
    }
    __syncthreads();

    // segmented prefix: seg owns y in [seg*28, seg*28+28), lane ol = o_local
    const int ol  = tid & 31;
    const int seg = tid >> 5;           // 0..7
    const int y0  = seg * 28;

    float ssum = 0.0f;
    #pragma unroll
    for (int i = 0; i < 28; ++i) ssum += lds[ol][y0 + i];
    carry[seg][ol] = ssum;
    __syncthreads();

    float s = 0.0f;
    for (int s2 = 0; s2 < seg; ++s2) s += carry[s2][ol];

    __hip_bfloat16* p = P + ((size_t)x * 225) * 256 + o0 + ol;
    if (seg == 0) p[0] = __float2bfloat16(0.0f);
    #pragma unroll
    for (int i = 0; i < 28; ++i) {
        s += lds[ol][y0 + i];
        p[(size_t)(y0 + i + 1) * 256] = __float2bfloat16(s);
    }
}

// ---------------- K2: per-batch argmax boxes + per-x run lists ----------------
// Emits entries runs[(b*224+x)*32 + j] (j<n) and dense cnt[b*224+x]=n.
// With inputs guaranteed py in [22,201], every y-interval is exactly 40 long
// -> <=5 disjoint runs; 12 slots is safe for the general case (<=11 possible).
__global__ void k_boxes_runs(const float* __restrict__ skel, uint32_t* __restrict__ runs,
                             uint8_t* __restrict__ cnt) {
    const int b = blockIdx.x;
    const int wave = threadIdx.x >> 6;
    const int t = threadIdx.x & 63;
    __shared__ int s_px[JD], s_ylo[JD], s_yhi[JD];

    const float* sb = skel + (size_t)b * JD * TD * 3;
    const float mx = sb[(MIDJ * TD + t) * 3 + 0];
    const float my = sb[(MIDJ * TD + t) * 3 + 1];
    const float mz = sb[(MIDJ * TD + t) * 3 + 2];

    for (int j = wave; j < JD; j += 4) {
        const float ax = sb[(j * TD + t) * 3 + 0];
        const float ay = sb[(j * TD + t) * 3 + 1];
        const float az = sb[(j * TD + t) * 3 + 2];
        const float dx = ax - mx, dy = ay - my, dz = az - mz;
        // match numpy: no fma contraction, left-to-right adds, IEEE sqrt
        const float d2 = __fadd_rn(__fadd_rn(__fmul_rn(dx, dx), __fmul_rn(dy, dy)),
                                   __fmul_rn(dz, dz));
        float bd = sqrtf(d2);
        int   bi = t;
        #pragma unroll
        for (int off = 1; off < 64; off <<= 1) {
            const float od = __shfl_xor(bd, off);
            const int   oi = __shfl_xor(bi, off);
            if (od > bd || (od == bd && oi < bi)) { bd = od; bi = oi; }
        }
        if (t == 0) {
            const float ptx = sb[(j * TD + bi) * 3 + 0];
            const float pty = sb[(j * TD + bi) * 3 + 1];
            const int px = (int)(ptx * 224.0f);
            const int py = (int)(pty * 224.0f);
            s_px[j]  = px;
            s_ylo[j] = (py < BOXR) ? 0 : (py - BOXR);
            s_yhi[j] = (py > IMG - BOXR) ? IMG : (py + BOXR);
        }
    }
    __syncthreads();

    const int x = threadIdx.x;
    if (x >= IMG) return;

    // 224-bit coverage bitmap over y, in 4 named u64 words
    unsigned long long m0 = 0, m1 = 0, m2 = 0, m3 = 0;
    for (int j = 0; j < JD; ++j) {
        if (j == MIDJ) continue;
        const int px = s_px[j];
        if (x >= px - BOXR && x < px + BOXR) {
            const int lo = s_ylo[j], hi = s_yhi[j];
            auto setw = [&](unsigned long long& mw, int wbase) {
                int l = lo - wbase; int h = hi - wbase;
                l = l < 0 ? 0 : l; h = h > 64 ? 64 : h;
                if (l < h) {
                    unsigned long long msk =
                        (h - l == 64) ? ~0ull : ((((1ull << (h - l)) - 1ull)) << l);
                    mw |= msk;
                }
            };
            setw(m0, 0); setw(m1, 64); setw(m2, 128); setw(m3, 192);
        }
    }

    uint32_t* rb = runs + ((size_t)b * IMG + x) * 32;
    int n = 0, start = -1;
    auto scanw = [&](unsigned long long bits, int wbase) {
        int pos = 0;
        while (pos < 64) {
            if (start < 0) {
                const unsigned long long tt = bits >> pos;
                if (!tt) return;
                pos += __builtin_ctzll(tt);
                start = wbase + pos;
            } else {
                const unsigned long long tt = (~bits) >> pos;
                if (!tt) return;
                pos += __builtin_ctzll(tt);
                rb[n] = (uint32_t)start | ((uint32_t)(wbase + pos) << 8);
                ++n; start = -1;
            }
        }
    };
    scanw(m0, 0); scanw(m1, 64); scanw(m2, 128); scanw(m3, 192);
    if (start >= 0) { rb[n] = (uint32_t)start | (224u << 8); ++n; }
    cnt[(size_t)b * IMG + x] = (uint8_t)n;
}

// ---------------- K3: accumulate run endpoint diffs over prefix table --------
// Three-phase to kill the round-2 28-deep dependent-load chain:
//   A: load 28 counts (1 round trip) + deterministic prefix offsets
//   B: gather all run entries into a flat LDS list (1 round trip)
//   C: stream endpoint vector loads from the flat list (pipelineable)
// blockIdx = b*8 + s keeps x-slice s on one XCD (3.2MB P slice fits 4MB L2).
__global__ void k_accum(const uint32_t* __restrict__ runs,
                        const uint8_t* __restrict__ cnt,
                        const uint32_t* __restrict__ P32,   // P viewed as bf16x2
                        float* __restrict__ part) {
    const int b = blockIdx.x >> 3;
    const int s = blockIdx.x & 7;
    const int tid = threadIdx.x;    // 0..127 -> outputs 2*tid, 2*tid+1
    const int x0 = s * 28;

    __shared__ uint8_t  scnt[28];
    __shared__ uint16_t soff[29];
    __shared__ uint32_t slist[28 * 12];

    if (tid < 28) scnt[tid] = cnt[(size_t)b * IMG + x0 + tid];
    __syncthreads();
    if (tid == 0) {
        uint16_t acc = 0;
        #pragma unroll
        for (int i = 0; i < 28; ++i) { soff[i] = acc; acc += scnt[i]; }
        soff[28] = acc;
    }
    __syncthreads();

    for (int e = tid; e < 28 * 12; e += 128) {
        const int xl = e / 12;
        const int j  = e - xl * 12;
        if (j < (int)scnt[xl]) {
            const uint32_t raw = runs[((size_t)b * IMG + x0 + xl) * 32 + j]; // bits 0..16
            slist[soff[xl] + j] = raw | ((uint32_t)xl << 17);
        }
    }
    __syncthreads();

    const int total = soff[28];
    float a0 = 0.0f, a1 = 0.0f;
    for (int i = 0; i < total; ++i) {
        const uint32_t e = slist[i];                  // LDS broadcast
        const int xl = (int)(e >> 17);
        const int a  = (int)(e & 255u);
        const int c  = (int)((e >> 8) & 511u);
        const uint32_t* px = P32 + (size_t)(x0 + xl) * 225 * 128 + tid;
        const uint32_t va = px[(size_t)a * 128];
        const uint32_t vc = px[(size_t)c * 128];
        a0 += __uint_as_float(vc << 16) - __uint_as_float(va << 16);
        a1 += __uint_as_float(vc & 0xffff0000u) - __uint_as_float(va & 0xffff0000u);
    }

    float* pp = part + (((size_t)b * 8 + s) * 256) + (size_t)tid * 2;
    pp[0] = a0;
    pp[1] = a1;
}

// ---------------- K4: out = rgb * (bias + sum of partials) -------------------
__global__ void k_final(const float* __restrict__ rgb, const float* __restrict__ bias,
                        const float* __restrict__ part, float* __restrict__ out) {
    const int idx = blockIdx.x * 256 + threadIdx.x;
    const int b = idx >> 8, o = idx & 255;
    float m = bias[o];
    #pragma unroll
    for (int s = 0; s < 8; ++s) m += part[(((size_t)b * 8 + s) * 256) + o];
    out[idx] = rgb[idx] * m;
}

extern "C" void kernel_launch(void* const* d_in, const int* in_sizes, int n_in,
                              void* d_out, int out_size, void* d_ws, size_t ws_size,
                              hipStream_t stream) {
    const float* rgb  = (const float*)d_in[0];
    const float* skel = (const float*)d_in[1];
    const float* W    = (const float*)d_in[2];
    const float* bias = (const float*)d_in[3];
    float* out = (float*)d_out;

    uint8_t* ws = (uint8_t*)d_ws;
    __hip_bfloat16* P = (__hip_bfloat16*)(ws);
    uint32_t* runs = (uint32_t*)(ws + OFF_RUNS);
    float* part = (float*)(ws + OFF_PART);
    uint8_t* cnt = (uint8_t*)(ws + OFF_CNT);

    k_wpref<<<dim3(IMG, 8), dim3(256), 0, stream>>>(W, P);
    k_boxes_runs<<<dim3(BATCH), dim3(256), 0, stream>>>(skel, runs, cnt);
    k_accum<<<dim3(BATCH * 8), dim3(128), 0, stream>>>(runs, cnt, (const uint32_t*)P, part);
    k_final<<<dim3(BATCH), dim3(256), 0, stream>>>(rgb, bias, part, out);
}